// Round 3
// baseline (530.762 us; speedup 1.0000x reference)
//
#include <hip/hip_runtime.h>
#include <hip/hip_bf16.h>

// Problem shapes (fixed by setup_inputs)
#define B_    1024
#define D_    768
#define POOL_ 100
#define PLEN_ 8
#define TOPK_ 3
#define EK_ELEMS (B_ * 4 * D_)           // 3,145,728
#define XB_ELEMS (B_ * 197 * D_)         // 154,976,256
#define XB_F4    (XB_ELEMS / 4)          // 38,744,064 float4s
#define CHUNK_F4 2048                    // 32 KB per copy chunk
#define NCHUNK   (XB_F4 / CHUNK_F4)      // 18,918 (exact, no tail)
#define NBLOCKS  1024
#define PREP_DONE_TARGET (100u * 256u)   // per-thread release adds

typedef float f4_t __attribute__((ext_vector_type(4)));

// ---------------------------------------------------------------------------
// One fused kernel, atomic work queue.
//   task < 100                     : prep row k=task  (softmax(A[k]) f64, nK[k] f64)
//   else u=task-100:
//     (u&15)==15 && (u>>4)<1024    : score+top3+gather for row b=u>>4
//     else                         : copy chunk c = u - min((u+1)>>4, 1024)
// Copy chunks interleave 15:1 with score tasks, so the HBM-bound passthrough
// runs concurrently with the L2/VALU-bound scoring.
// Deadlock-free: prep tasks are the first 100 claims; a claimant is by
// definition a resident, running block, so the prep-done counter always
// advances; score tasks spin on it with device-scope acquire.
// ---------------------------------------------------------------------------
__global__ void __launch_bounds__(256, 4)
fused_kernel(const float* __restrict__ xq, const float* __restrict__ xb,
             const float* __restrict__ K, const float* __restrict__ A,
             const float* __restrict__ p, float* __restrict__ out,
             double* __restrict__ sm, double* __restrict__ nK,
             unsigned int* __restrict__ ctr /* [0]=task, [1]=prep_done */) {
    __shared__ double s_xq[D_];
    __shared__ double s_aq[POOL_];
    __shared__ double red[4];
    __shared__ int    s_task;
    __shared__ int    s_idx[TOPK_];

    const int t = threadIdx.x;
    const int wave = t >> 6, lane = t & 63;

    for (;;) {
        if (t == 0)
            s_task = (int)__hip_atomic_fetch_add(&ctr[0], 1u, __ATOMIC_RELAXED,
                                                 __HIP_MEMORY_SCOPE_AGENT);
        __syncthreads();
        const int task = s_task;

        if (task < POOL_) {
            // ---------------- prep row k ----------------
            const int k = task;
            double m = -1e300;
            for (int d = t; d < D_; d += 256) m = fmax(m, (double)A[k * D_ + d]);
            #pragma unroll
            for (int off = 32; off >= 1; off >>= 1) m = fmax(m, __shfl_xor(m, off));
            if (lane == 0) red[wave] = m;
            __syncthreads();
            m = fmax(fmax(red[0], red[1]), fmax(red[2], red[3]));
            __syncthreads();

            double s = 0.0;
            for (int d = t; d < D_; d += 256) s += exp((double)A[k * D_ + d] - m);
            #pragma unroll
            for (int off = 32; off >= 1; off >>= 1) s += __shfl_xor(s, off);
            if (lane == 0) red[wave] = s;
            __syncthreads();
            s = red[0] + red[1] + red[2] + red[3];
            __syncthreads();

            for (int d = t; d < D_; d += 256)
                sm[k * D_ + d] = exp((double)A[k * D_ + d] - m) / s;

            double ss = 0.0;
            for (int d = t; d < D_; d += 256) {
                double v = (double)K[k * D_ + d];
                ss += v * v;
            }
            #pragma unroll
            for (int off = 32; off >= 1; off >>= 1) ss += __shfl_xor(ss, off);
            if (lane == 0) red[wave] = ss;
            __syncthreads();
            ss = red[0] + red[1] + red[2] + red[3];
            const double n = fmax(sqrt(ss), 1e-12);

            for (int d = t; d < D_; d += 256)
                nK[k * D_ + d] = (double)K[k * D_ + d] / n;

            __syncthreads();
            // per-thread release: each thread's own stores are ordered
            __hip_atomic_fetch_add(&ctr[1], 1u, __ATOMIC_RELEASE,
                                   __HIP_MEMORY_SCOPE_AGENT);
        } else {
            const unsigned u = (unsigned)(task - POOL_);
            const bool is_score = ((u & 15u) == 15u) && ((u >> 4) < (unsigned)B_);
            if (is_score) {
                // ---------------- score + top3 + gather, row b ----------------
                const int b = (int)(u >> 4);
                if (t == 0) {
                    while (__hip_atomic_load(&ctr[1], __ATOMIC_ACQUIRE,
                                             __HIP_MEMORY_SCOPE_AGENT) < PREP_DONE_TARGET)
                        __builtin_amdgcn_s_sleep(8);
                }
                __syncthreads();

                for (int d = t; d < D_; d += 256) s_xq[d] = (double)xq[b * D_ + d];
                __syncthreads();

                for (int k = wave; k < POOL_; k += 4) {
                    const double* __restrict__ smk = sm + (size_t)k * D_;
                    const double* __restrict__ nkk = nK + (size_t)k * D_;
                    double dot = 0.0, sq = 0.0;
                    for (int d = lane; d < D_; d += 64) {
                        double v = s_xq[d] * smk[d];
                        dot += v * nkk[d];
                        sq  += v * v;
                    }
                    #pragma unroll
                    for (int off = 32; off >= 1; off >>= 1) {
                        dot += __shfl_xor(dot, off);
                        sq  += __shfl_xor(sq, off);
                    }
                    if (lane == 0) s_aq[k] = dot / fmax(sqrt(sq), 1e-12);
                }
                __syncthreads();

                if (t == 0) {
                    #pragma unroll
                    for (int r = 0; r < TOPK_; ++r) {
                        double best = -1e300; int bi = 0;
                        for (int kk = 0; kk < POOL_; ++kk)
                            if (s_aq[kk] > best) { best = s_aq[kk]; bi = kk; }
                        s_idx[r] = bi;
                        s_aq[bi] = -1e300;
                    }
                }
                __syncthreads();
                const int i0 = s_idx[0], i1 = s_idx[1], i2 = s_idx[2];

                // gather: 8 rows x 192 float4 = 1536 tasks over 256 threads
                for (int w = t; w < PLEN_ * 192; w += 256) {
                    const int j = w / 192, c = w % 192;
                    const f4_t* __restrict__ q0 = (const f4_t*)(p + (size_t)(j * POOL_ + i0) * D_);
                    const f4_t* __restrict__ q1 = (const f4_t*)(p + (size_t)(j * POOL_ + i1) * D_);
                    const f4_t* __restrict__ q2 = (const f4_t*)(p + (size_t)(j * POOL_ + i2) * D_);
                    f4_t r = q0[c] + q1[c] + q2[c];
                    float* dst = (j < 4) ? out + ((size_t)b * 4 + j) * D_
                                         : out + EK_ELEMS + ((size_t)b * 4 + (j - 4)) * D_;
                    ((f4_t*)dst)[c] = r;
                }
            } else {
                // ---------------- copy chunk ----------------
                unsigned sb = (u + 1u) >> 4;
                if (sb > (unsigned)B_) sb = (unsigned)B_;
                const unsigned c = u - sb;
                if (c >= (unsigned)NCHUNK) break;

                const f4_t* __restrict__ src = (const f4_t*)xb;
                f4_t* __restrict__ dst = (f4_t*)(out + 2 * (size_t)EK_ELEMS);
                const size_t base = (size_t)c * CHUNK_F4;
                #pragma unroll
                for (int i = 0; i < CHUNK_F4 / 256; ++i) {
                    const size_t ix = base + (size_t)i * 256 + t;
                    f4_t v = __builtin_nontemporal_load(&src[ix]);
                    __builtin_nontemporal_store(v, &dst[ix]);
                }
            }
        }
        __syncthreads();   // protect s_task / shared reuse across iterations
    }
}

extern "C" void kernel_launch(void* const* d_in, const int* in_sizes, int n_in,
                              void* d_out, int out_size, void* d_ws, size_t ws_size,
                              hipStream_t stream) {
    const float* x_querry = (const float*)d_in[0];   // (1024, 768)
    const float* x_block  = (const float*)d_in[1];   // (1024, 197, 768)
    const float* K        = (const float*)d_in[2];   // (100, 768)
    const float* A        = (const float*)d_in[3];   // (100, 768)
    const float* p        = (const float*)d_in[4];   // (8, 100, 768)
    // d_in[5] = l (unused)

    float* out = (float*)d_out;

    // workspace layout
    double* sm        = (double*)d_ws;                     // 100*768 f64
    double* nK        = sm + (size_t)POOL_ * D_;           // 100*768 f64
    unsigned int* ctr = (unsigned int*)(nK + (size_t)POOL_ * D_);  // 2 x u32

    hipMemsetAsync(ctr, 0, 2 * sizeof(unsigned int), stream);
    fused_kernel<<<NBLOCKS, 256, 0, stream>>>(x_querry, x_block, K, A, p,
                                              out, sm, nK, ctr);
}